// Round 4
// baseline (200.058 us; speedup 1.0000x reference)
//
#include <hip/hip_runtime.h>
#include <hip/hip_bf16.h>

// Problem constants (fixed by reference): B=8, C=128, N=M=4096, OUT=128
#define BATCH 8
#define CDIM 128
#define NDIM 4096

typedef __bf16 bf16x8 __attribute__((ext_vector_type(8)));
typedef float f32x4 __attribute__((ext_vector_type(4)));

// workspace layout (bytes)
#define QT_OFF 0u                      // bf16 [8][4096][128]  normalized target_g, transposed
#define KT_OFF 8388608u                // bf16 [8][4096][128]  normalized input, transposed
#define VB_OFF 16777216u               // bf16 [8][128][4096]  raw input
#define WT_OFF 25165824u               // bf16 [128][128]      weight transposed: wT[o][c]
#define SC_OFF (WT_OFF + 32768u)       // f32 [128] scale = gamma*rsqrt(var+eps)
#define BI_OFF (SC_OFF + 512u)         // f32 [128] bias  = beta - mean*scale

__device__ __forceinline__ f32x4 mfma16(bf16x8 a, bf16x8 b, f32x4 c) {
    return __builtin_amdgcn_mfma_f32_16x16x32_bf16(a, b, c, 0, 0, 0);
}

__device__ __forceinline__ unsigned pack2bf(float a, float b) {
    unsigned short ul = __builtin_bit_cast(unsigned short, (__bf16)a);
    unsigned short uh = __builtin_bit_cast(unsigned short, (__bf16)b);
    return (unsigned)ul | ((unsigned)uh << 16);
}

__device__ __forceinline__ void glds16(const void* g, void* l) {
    __builtin_amdgcn_global_load_lds((__attribute__((address_space(1))) void*)(void*)g,
                                     (__attribute__((address_space(3))) void*)l, 16, 0, 0);
}

// ---------------------------------------------------------------------------
// Pass 1a: per-column L2 normalize over C + transpose to [n][c] bf16.
// ---------------------------------------------------------------------------
__global__ __launch_bounds__(256) void prep_nt(const float* __restrict__ input,
                                               const float* __restrict__ tg,
                                               void* __restrict__ ws) {
    __shared__ float Tt[64][129];     // [n-local][c], pitch 129
    __shared__ float psum[4][64];
    __shared__ float rn[64];
    const int n0 = blockIdx.x * 64;
    const int b  = blockIdx.y;
    const int tid = threadIdx.x;
    const float* src = (blockIdx.z == 0 ? input : tg) + (size_t)b * CDIM * NDIM;

    #pragma unroll
    for (int i = 0; i < 8; ++i) {
        int f = tid + i * 256;
        int c = f >> 4, j4 = f & 15;
        float4 v = *(const float4*)(src + (size_t)c * NDIM + n0 + j4 * 4);
        Tt[j4 * 4 + 0][c] = v.x;
        Tt[j4 * 4 + 1][c] = v.y;
        Tt[j4 * 4 + 2][c] = v.z;
        Tt[j4 * 4 + 3][c] = v.w;
    }
    __syncthreads();
    {
        int j = tid & 63, part = tid >> 6;
        float ss = 0.f;
        #pragma unroll 8
        for (int c = part * 32; c < part * 32 + 32; ++c) { float x = Tt[j][c]; ss += x * x; }
        psum[part][j] = ss;
    }
    __syncthreads();
    if (tid < 64) {
        float s = psum[0][tid] + psum[1][tid] + psum[2][tid] + psum[3][tid];
        rn[tid] = 1.0f / fmaxf(sqrtf(s), 1e-12f);
    }
    __syncthreads();

    __hip_bfloat16* dstT = (__hip_bfloat16*)((char*)ws + (blockIdx.z == 0 ? KT_OFF : QT_OFF))
                           + ((size_t)b * NDIM + n0) * CDIM;
    #pragma unroll
    for (int i = 0; i < 8; ++i) {
        int f = tid + i * 256;
        int j = f >> 5, c4 = f & 31;
        float r = rn[j];
        float4 v = *(const float4*)&Tt[j][c4 * 4];
        uint2 pk; pk.x = pack2bf(v.x * r, v.y * r); pk.y = pack2bf(v.z * r, v.w * r);
        *(uint2*)((unsigned short*)dstT + (size_t)j * CDIM + c4 * 4) = pk;
    }
    if (blockIdx.z == 0) {
        __hip_bfloat16* vb = (__hip_bfloat16*)((char*)ws + VB_OFF) + (size_t)b * CDIM * NDIM + n0;
        #pragma unroll
        for (int i = 0; i < 8; ++i) {
            int f = tid + i * 256;
            int c = f >> 4, j4 = f & 15;
            float x0 = Tt[j4 * 4 + 0][c], x1 = Tt[j4 * 4 + 1][c];
            float x2 = Tt[j4 * 4 + 2][c], x3 = Tt[j4 * 4 + 3][c];
            uint2 pv; pv.x = pack2bf(x0, x1); pv.y = pack2bf(x2, x3);
            *(uint2*)((unsigned short*)vb + (size_t)c * NDIM + j4 * 4) = pv;
        }
    }
}

// ---------------------------------------------------------------------------
// Pass 1b: transpose weight to bf16 wT[o][c]; fold BN into scale/bias.
// ---------------------------------------------------------------------------
__global__ __launch_bounds__(256) void prep_w(const float* __restrict__ wgt,
                                              const float* __restrict__ gamma,
                                              const float* __restrict__ beta,
                                              const float* __restrict__ mean,
                                              const float* __restrict__ var,
                                              void* __restrict__ ws) {
    __hip_bfloat16* wT = (__hip_bfloat16*)((char*)ws + WT_OFF);
    float* sc = (float*)((char*)ws + SC_OFF);
    float* bi = (float*)((char*)ws + BI_OFF);
    const int tid = threadIdx.x;
    #pragma unroll
    for (int i = 0; i < 64; ++i) {
        int f = tid + i * 256;
        int c = f >> 7, o = f & 127;
        wT[o * 128 + c] = __hip_bfloat16(wgt[c * 128 + o]);
    }
    if (tid < 128) {
        float inv = rsqrtf(var[tid] + 1e-5f);
        float s = inv * gamma[tid];
        sc[tid] = s;
        bi[tid] = beta[tid] - mean[tid] * s;
    }
}

// ---------------------------------------------------------------------------
// Pass 2 (flash4): software-pipelined K-loop, raw barriers, dbuf K/V staging.
// 512 thr = 8 waves; grid 512 1-D: batch = bx&7 (XCD L2 locality), mt = bx>>3.
// Per 64-n iteration:
//   B: s_waitcnt vmcnt(0) lgkmcnt(0); s_barrier   (tile(it) ready — its glds
//      were issued one full iteration ago; latency hidden by exp+PV(it-1))
//   S^T = K·Q^T  (wave = 16n × 32m; kf from LDS, qf resident)
//   P = exp(S-1) → LDS (single buffer, 8 KB)
//   prefetch glds tile(it+1) → other buffer  (stays in flight across C!)
//   C: s_waitcnt lgkmcnt(0); s_barrier            (P visible; vmcnt NOT drained)
//   O^T += V·P^T (wave = 32c × 32m)
// LDS: buf0 K@0 V@16K, buf1 K@32K V@48K, P@64K..72K. Epilogue reuse:
// sRes f32[128][68]@0, lLds f32[4][64]@34816, sAgg bf16[64][128]swz@36864.
// ---------------------------------------------------------------------------
__global__ __launch_bounds__(512, 4) void flash4(const void* __restrict__ ws_,
                                                 float* __restrict__ out) {
    extern __shared__ char smem[];
    const char* ws = (const char*)ws_;
    const __hip_bfloat16* Qt = (const __hip_bfloat16*)(ws + QT_OFF);
    const __hip_bfloat16* Kt = (const __hip_bfloat16*)(ws + KT_OFF);
    const __hip_bfloat16* Vb = (const __hip_bfloat16*)(ws + VB_OFF);
    const __hip_bfloat16* wT = (const __hip_bfloat16*)(ws + WT_OFF);
    const float* scale = (const float*)(ws + SC_OFF);
    const float* bias  = (const float*)(ws + BI_OFF);

    const int bx = blockIdx.x;
    const int b  = bx & 7;
    const int m0 = (bx >> 3) * 64;
    const int tid = threadIdx.x;
    const int w = tid >> 6, lane = tid & 63;
    const int li = lane & 15, q = lane >> 4;
    const int ns = w & 3, msS = w >> 2;     // S-split: 4×16n, 2×32m
    const int cs = w & 3, msP = w >> 2;     // PV-split: 4×32c, 2×32m

    const __hip_bfloat16* kgb = Kt + (size_t)b * NDIM * CDIM;
    const __hip_bfloat16* vgb = Vb + (size_t)b * CDIM * NDIM;

    // resident Q B-frags: m = msS*32 + mb*16 + li
    bf16x8 qf[2][4];
    #pragma unroll
    for (int mb = 0; mb < 2; ++mb) {
        const __hip_bfloat16* qrow = Qt + ((size_t)b * NDIM + m0 + msS * 32 + mb * 16 + li) * CDIM;
        #pragma unroll
        for (int ks = 0; ks < 4; ++ks)
            qf[mb][ks] = *(const bf16x8*)(qrow + ks * 32 + q * 8);
    }

    // loop-invariant LDS byte offsets
    unsigned kOff[4];                       // S kf reads: row n = ns*16+li, 16-slot swz^(n&7)
    {
        int n = ns * 16 + li;
        #pragma unroll
        for (int ks = 0; ks < 4; ++ks)
            kOff[ks] = n * 256 + (((ks * 4 + q) ^ (n & 7)) * 16);
    }
    unsigned vOff[2][2];                    // PV vf reads: row c = cs*32+ca*16+li, 8-slot swz
    #pragma unroll
    for (int ca = 0; ca < 2; ++ca) {
        int c = cs * 32 + ca * 16 + li;
        #pragma unroll
        for (int k2 = 0; k2 < 2; ++k2)
            vOff[ca][k2] = 16384 + c * 128 + (((k2 * 4 + q) ^ (c & 7)) * 16);
    }
    unsigned pOff[2][2];                    // PV pf reads
    #pragma unroll
    for (int mb = 0; mb < 2; ++mb) {
        int m = msP * 32 + mb * 16 + li;
        #pragma unroll
        for (int k2 = 0; k2 < 2; ++k2)
            pOff[mb][k2] = 65536 + m * 128 + (((k2 * 4 + q) ^ (m & 7)) * 16);
    }
    unsigned pwOff[2];                      // P writes (8B packed, n-quad at ns*16+q*4)
    #pragma unroll
    for (int mb = 0; mb < 2; ++mb) {
        int m = msS * 32 + mb * 16 + li;
        pwOff[mb] = 65536 + m * 128 + (((ns * 2 + (q >> 1)) ^ (m & 7)) * 16) + (q & 1) * 8;
    }

    // staging sources (per-lane gathered; LDS dst = wave-uniform base + lane*16)
    const char* kSrc[2]; const char* vSrc[2];
    unsigned kDst[2], vDst[2];
    #pragma unroll
    for (int i = 0; i < 2; ++i) {
        int d = (w * 2 + i) * 64 + lane;
        int n = d >> 4, sz = d & 15;
        int s = (sz & 8) | ((sz & 7) ^ (n & 7));
        kSrc[i] = (const char*)kgb + n * 256 + s * 16;
        kDst[i] = (w * 2 + i) * 1024;
        int c = d >> 3, sz8 = d & 7;
        int s8 = sz8 ^ (c & 7);
        vSrc[i] = (const char*)vgb + (size_t)c * 8192 + s8 * 16;
        vDst[i] = 16384 + (w * 2 + i) * 1024;
    }

    const f32x4 z4 = {0.f, 0.f, 0.f, 0.f};
    f32x4 oacc[2][2];
    oacc[0][0] = z4; oacc[0][1] = z4; oacc[1][0] = z4; oacc[1][1] = z4;
    float lac0 = 0.f, lac1 = 0.f;

    // prologue: stage tile 0 into buf0
    #pragma unroll
    for (int i = 0; i < 2; ++i) { glds16(kSrc[i], smem + kDst[i]); kSrc[i] += 16384; }
    #pragma unroll
    for (int i = 0; i < 2; ++i) { glds16(vSrc[i], smem + vDst[i]); vSrc[i] += 128; }

    auto body = [&](const unsigned bo, const bool do_pref) {
        // B: tile(it) ready; the only outstanding vmem is tile(it)'s glds,
        // issued one iteration ago (or prologue) — latency already covered.
        asm volatile("s_waitcnt vmcnt(0) lgkmcnt(0)\ns_barrier" ::: "memory");

        // S^T = K·Q^T
        f32x4 st0 = z4, st1 = z4;
        #pragma unroll
        for (int ks = 0; ks < 4; ++ks) {
            bf16x8 kf = *(const bf16x8*)(smem + bo + kOff[ks]);
            st0 = mfma16(kf, qf[0][ks], st0);
            st1 = mfma16(kf, qf[1][ks], st1);
        }
        // P = exp(S-1), accumulate l, packed 8B writes
        {
            float p0 = __expf(st0[0] - 1.0f), p1 = __expf(st0[1] - 1.0f);
            float p2 = __expf(st0[2] - 1.0f), p3 = __expf(st0[3] - 1.0f);
            lac0 += (p0 + p1) + (p2 + p3);
            uint2 pk; pk.x = pack2bf(p0, p1); pk.y = pack2bf(p2, p3);
            *(uint2*)(smem + pwOff[0]) = pk;
        }
        {
            float p0 = __expf(st1[0] - 1.0f), p1 = __expf(st1[1] - 1.0f);
            float p2 = __expf(st1[2] - 1.0f), p3 = __expf(st1[3] - 1.0f);
            lac1 += (p0 + p1) + (p2 + p3);
            uint2 pk; pk.x = pack2bf(p0, p1); pk.y = pack2bf(p2, p3);
            *(uint2*)(smem + pwOff[1]) = pk;
        }
        // prefetch tile(it+1) into the other buffer; stays in flight across C
        if (do_pref) {
            const unsigned obo = bo ^ 32768u;
            #pragma unroll
            for (int i = 0; i < 2; ++i) { glds16(kSrc[i], smem + (obo + kDst[i])); kSrc[i] += 16384; }
            #pragma unroll
            for (int i = 0; i < 2; ++i) { glds16(vSrc[i], smem + (obo + vDst[i])); vSrc[i] += 128; }
        }
        // C: P visible; vmcnt deliberately NOT drained
        asm volatile("s_waitcnt lgkmcnt(0)\ns_barrier" ::: "memory");

        // O^T += V·P^T
        #pragma unroll
        for (int k2 = 0; k2 < 2; ++k2) {
            bf16x8 pf0 = *(const bf16x8*)(smem + pOff[0][k2]);
            bf16x8 pf1 = *(const bf16x8*)(smem + pOff[1][k2]);
            bf16x8 vf0 = *(const bf16x8*)(smem + bo + vOff[0][k2]);
            bf16x8 vf1 = *(const bf16x8*)(smem + bo + vOff[1][k2]);
            oacc[0][0] = mfma16(vf0, pf0, oacc[0][0]);
            oacc[0][1] = mfma16(vf0, pf1, oacc[0][1]);
            oacc[1][0] = mfma16(vf1, pf0, oacc[1][0]);
            oacc[1][1] = mfma16(vf1, pf1, oacc[1][1]);
        }
    };

    for (int ii = 0; ii < 32; ++ii) {
        body(0u, true);
        body(32768u, ii != 31);
    }

    // ---- epilogue ----
    lac0 += __shfl_xor(lac0, 16, 64); lac0 += __shfl_xor(lac0, 32, 64);
    lac1 += __shfl_xor(lac1, 16, 64); lac1 += __shfl_xor(lac1, 32, 64);

    __syncthreads();                                   // E1: loop fully done
    float* lLds = (float*)(smem + 34816);              // [4][64] partials (per ns)
    if (q == 0) {
        lLds[ns * 64 + msS * 32 + li] = lac0;
        lLds[ns * 64 + msS * 32 + 16 + li] = lac1;
    }
    __syncthreads();                                   // E2
    __hip_bfloat16* sAgg = (__hip_bfloat16*)(smem + 36864);  // [64 m][128 c] swz
    {
        float linv[2]; int mm[2];
        #pragma unroll
        for (int mb = 0; mb < 2; ++mb) {
            int m = msP * 32 + mb * 16 + li;
            mm[mb] = m;
            linv[mb] = 1.0f / (lLds[m] + lLds[64 + m] + lLds[128 + m] + lLds[192 + m]);
        }
        #pragma unroll
        for (int ca = 0; ca < 2; ++ca) {
            #pragma unroll
            for (int mb = 0; mb < 2; ++mb) {
                int m = mm[mb];
                float v0 = oacc[ca][mb][0] * linv[mb];
                float v1 = oacc[ca][mb][1] * linv[mb];
                float v2 = oacc[ca][mb][2] * linv[mb];
                float v3 = oacc[ca][mb][3] * linv[mb];
                uint2 pk; pk.x = pack2bf(v0, v1); pk.y = pack2bf(v2, v3);
                int c8 = cs * 8 + ca * 4 + q;          // c-quad 0..31
                int slot8 = c8 ^ ((li & 7) << 1);
                *(uint2*)((char*)sAgg + m * 256 + slot8 * 8) = pk;
            }
        }
    }
    __syncthreads();                                   // E3: sAgg ready

    // projection: wave -> m-slice (w&3)*16, o-half (w>>2)*64
    const int mslice = (w & 3) * 16;
    const int ohalf = (w >> 2) * 64;
    f32x4 racc[4];
    #pragma unroll
    for (int ob = 0; ob < 4; ++ob) racc[ob] = z4;
    #pragma unroll
    for (int ks = 0; ks < 4; ++ks) {
        int slot8 = ((ks * 4 + q) * 2) ^ ((li & 7) << 1);
        bf16x8 af = *(const bf16x8*)((char*)sAgg + (mslice + li) * 256 + slot8 * 8);
        #pragma unroll
        for (int ob = 0; ob < 4; ++ob) {
            bf16x8 wf = *(const bf16x8*)(wT + (size_t)(ohalf + ob * 16 + li) * CDIM + ks * 32 + q * 8);
            racc[ob] = mfma16(af, wf, racc[ob]);
        }
    }

    // LeakyReLU + BN(eval) -> transpose buffer
    float* sRes = (float*)smem;                        // [128][68]
    #pragma unroll
    for (int ob = 0; ob < 4; ++ob) {
        int o = ohalf + ob * 16 + li;
        float sc = scale[o], bi = bias[o];
        #pragma unroll
        for (int r = 0; r < 4; ++r) {
            float v = racc[ob][r];
            v = (v >= 0.0f) ? v : 0.01f * v;
            v = v * sc + bi;
            sRes[o * 68 + mslice + q * 4 + r] = v;
        }
    }
    __syncthreads();                                   // E4

    // coalesced store: out[b][o][m0..m0+63]
    float* outb = out + (size_t)b * CDIM * NDIM + m0;
    #pragma unroll
    for (int i = 0; i < 4; ++i) {
        int f = tid + i * 512;
        int o = f >> 4, mq = f & 15;
        *(float4*)(outb + (size_t)o * NDIM + mq * 4) = *(const float4*)(sRes + o * 68 + mq * 4);
    }
}

extern "C" void kernel_launch(void* const* d_in, const int* in_sizes, int n_in,
                              void* d_out, int out_size, void* d_ws, size_t ws_size,
                              hipStream_t stream) {
    const float* input  = (const float*)d_in[0];
    const float* tg     = (const float*)d_in[1];
    const float* weight = (const float*)d_in[2];
    const float* gamma  = (const float*)d_in[3];
    const float* beta   = (const float*)d_in[4];
    const float* rmean  = (const float*)d_in[5];
    const float* rvar   = (const float*)d_in[6];
    float* out = (float*)d_out;

    (void)in_sizes; (void)n_in; (void)out_size; (void)ws_size;

    hipFuncSetAttribute(reinterpret_cast<const void*>(flash4),
                        hipFuncAttributeMaxDynamicSharedMemorySize, 73728);

    dim3 gprep(NDIM / 64, BATCH, 2);
    prep_nt<<<gprep, 256, 0, stream>>>(input, tg, d_ws);
    prep_w<<<dim3(1), 256, 0, stream>>>(weight, gamma, beta, rmean, rvar, d_ws);
    flash4<<<dim3(512), 512, 73728, stream>>>(d_ws, out);
}

// Round 5
// 190.396 us; speedup vs baseline: 1.0507x; 1.0507x over previous
//
#include <hip/hip_runtime.h>
#include <hip/hip_bf16.h>

// Problem constants (fixed by reference): B=8, C=128, N=M=4096, OUT=128
#define BATCH 8
#define CDIM 128
#define NDIM 4096

typedef __bf16 bf16x8 __attribute__((ext_vector_type(8)));
typedef float f32x4 __attribute__((ext_vector_type(4)));
typedef float f32x16 __attribute__((ext_vector_type(16)));
typedef unsigned u32x4 __attribute__((ext_vector_type(4)));

// workspace layout (bytes)
#define QT_OFF 0u                      // bf16 [8][4096][128]  normalized target_g, transposed
#define KT_OFF 8388608u                // bf16 [8][4096][128]  normalized input, transposed
#define VB_OFF 16777216u               // bf16 [8][128][4096]  raw input
#define WT_OFF 25165824u               // bf16 [128][128]      weight transposed: wT[o][c]
#define SC_OFF (WT_OFF + 32768u)       // f32 [128] scale = gamma*rsqrt(var+eps)
#define BI_OFF (SC_OFF + 512u)         // f32 [128] bias  = beta - mean*scale

__device__ __forceinline__ f32x4 mfma16(bf16x8 a, bf16x8 b, f32x4 c) {
    return __builtin_amdgcn_mfma_f32_16x16x32_bf16(a, b, c, 0, 0, 0);
}
__device__ __forceinline__ f32x16 mfma32(bf16x8 a, bf16x8 b, f32x16 c) {
    return __builtin_amdgcn_mfma_f32_32x32x16_bf16(a, b, c, 0, 0, 0);
}

__device__ __forceinline__ unsigned pack2bf(float a, float b) {
    unsigned short ul = __builtin_bit_cast(unsigned short, (__bf16)a);
    unsigned short uh = __builtin_bit_cast(unsigned short, (__bf16)b);
    return (unsigned)ul | ((unsigned)uh << 16);
}

__device__ __forceinline__ void glds16(const void* g, void* l) {
    __builtin_amdgcn_global_load_lds((__attribute__((address_space(1))) void*)(void*)g,
                                     (__attribute__((address_space(3))) void*)l, 16, 0, 0);
}

// ---------------------------------------------------------------------------
// Pass 1: per-column L2 normalize over C + transpose to [n][c] bf16.
// z==0: input -> Kt + Vb ; z==1: target_g -> Qt (+ one block does W/BN fold)
// ---------------------------------------------------------------------------
__global__ __launch_bounds__(256) void prep_nt(const float* __restrict__ input,
                                               const float* __restrict__ tg,
                                               const float* __restrict__ wgt,
                                               const float* __restrict__ gamma,
                                               const float* __restrict__ beta,
                                               const float* __restrict__ mean,
                                               const float* __restrict__ var,
                                               void* __restrict__ ws) {
    __shared__ float Tt[64][129];     // [n-local][c], pitch 129
    __shared__ float psum[4][64];
    __shared__ float rn[64];
    const int n0 = blockIdx.x * 64;
    const int b  = blockIdx.y;
    const int tid = threadIdx.x;
    const float* src = (blockIdx.z == 0 ? input : tg) + (size_t)b * CDIM * NDIM;

    #pragma unroll
    for (int i = 0; i < 8; ++i) {
        int f = tid + i * 256;
        int c = f >> 4, j4 = f & 15;
        float4 v = *(const float4*)(src + (size_t)c * NDIM + n0 + j4 * 4);
        Tt[j4 * 4 + 0][c] = v.x;
        Tt[j4 * 4 + 1][c] = v.y;
        Tt[j4 * 4 + 2][c] = v.z;
        Tt[j4 * 4 + 3][c] = v.w;
    }
    __syncthreads();
    {
        int j = tid & 63, part = tid >> 6;
        float ss = 0.f;
        #pragma unroll 8
        for (int c = part * 32; c < part * 32 + 32; ++c) { float x = Tt[j][c]; ss += x * x; }
        psum[part][j] = ss;
    }
    __syncthreads();
    if (tid < 64) {
        float s = psum[0][tid] + psum[1][tid] + psum[2][tid] + psum[3][tid];
        rn[tid] = 1.0f / fmaxf(sqrtf(s), 1e-12f);
    }
    __syncthreads();

    __hip_bfloat16* dstT = (__hip_bfloat16*)((char*)ws + (blockIdx.z == 0 ? KT_OFF : QT_OFF))
                           + ((size_t)b * NDIM + n0) * CDIM;
    #pragma unroll
    for (int i = 0; i < 8; ++i) {
        int f = tid + i * 256;
        int j = f >> 5, c4 = f & 31;
        float r = rn[j];
        float4 v = *(const float4*)&Tt[j][c4 * 4];
        uint2 pk; pk.x = pack2bf(v.x * r, v.y * r); pk.y = pack2bf(v.z * r, v.w * r);
        *(uint2*)((unsigned short*)dstT + (size_t)j * CDIM + c4 * 4) = pk;
    }
    if (blockIdx.z == 0) {
        __hip_bfloat16* vb = (__hip_bfloat16*)((char*)ws + VB_OFF) + (size_t)b * CDIM * NDIM + n0;
        #pragma unroll
        for (int i = 0; i < 8; ++i) {
            int f = tid + i * 256;
            int c = f >> 4, j4 = f & 15;
            float x0 = Tt[j4 * 4 + 0][c], x1 = Tt[j4 * 4 + 1][c];
            float x2 = Tt[j4 * 4 + 2][c], x3 = Tt[j4 * 4 + 3][c];
            uint2 pv; pv.x = pack2bf(x0, x1); pv.y = pack2bf(x2, x3);
            *(uint2*)((unsigned short*)vb + (size_t)c * NDIM + j4 * 4) = pv;
        }
    } else if (blockIdx.x == 0 && b == 0) {
        // folded prep_w
        __hip_bfloat16* wT = (__hip_bfloat16*)((char*)ws + WT_OFF);
        float* sc = (float*)((char*)ws + SC_OFF);
        float* bi = (float*)((char*)ws + BI_OFF);
        #pragma unroll
        for (int i = 0; i < 64; ++i) {
            int f = tid + i * 256;
            int c = f >> 7, o = f & 127;
            wT[o * 128 + c] = __hip_bfloat16(wgt[c * 128 + o]);
        }
        if (tid < 128) {
            float inv = rsqrtf(var[tid] + 1e-5f);
            float s = inv * gamma[tid];
            sc[tid] = s;
            bi[tid] = beta[tid] - mean[tid] * s;
        }
    }
}

// ---------------------------------------------------------------------------
// Pass 2 (flash5): 32x32x16 MFMA, P kept in registers (C-layout -> B-operand
// via pack + shfl_xor(32) half-swap), ONE barrier per 64-n body.
// Grid 256 (1 block/CU), batch = bx&7 (XCD-pinned), m-tile = 128.
// 512 thr = 8 waves: wave = (nt = w&1 n-half of the 64-n tile, mt = w>>1
// m-quarter). S^T = K·Q^T (A=K from LDS, B=Q resident); O^T += V·P^T
// (A=V from LDS, B=P in regs). l = plain f32 lane sums.
// LDS: dbuf K16K+V16K @0/@32K (64 KB). Epilogue: oStg f32 64KB@0,
// lLds f32[8][32]@65536, sAgg bf16[128][128]swz@67584, sRes f32[128][132]@0.
// ---------------------------------------------------------------------------
__global__ __launch_bounds__(512, 2) void flash5(const void* __restrict__ ws_,
                                                 float* __restrict__ out) {
    extern __shared__ char smem[];
    const char* ws = (const char*)ws_;
    const __hip_bfloat16* Qt = (const __hip_bfloat16*)(ws + QT_OFF);
    const __hip_bfloat16* Kt = (const __hip_bfloat16*)(ws + KT_OFF);
    const __hip_bfloat16* Vb = (const __hip_bfloat16*)(ws + VB_OFF);
    const __hip_bfloat16* wT = (const __hip_bfloat16*)(ws + WT_OFF);
    const float* scale = (const float*)(ws + SC_OFF);
    const float* bias  = (const float*)(ws + BI_OFF);

    const int bx = blockIdx.x;
    const int b  = bx & 7;
    const int m0 = (bx >> 3) * 128;
    const int tid = threadIdx.x;
    const int w = tid >> 6, lane = tid & 63;
    const int hf = lane >> 5;          // lane half
    const int l31 = lane & 31;
    const int nt = w & 1;              // n-subtile of the 64-n body
    const int mt = w >> 1;             // m-subtile (0..3)

    const char* kgb = (const char*)(Kt + (size_t)b * NDIM * CDIM);
    const char* vgb = (const char*)(Vb + (size_t)b * CDIM * NDIM);

    // resident Q B-frags: B[k=c][col=m], col = l31 -> m = m0 + mt*32 + l31
    bf16x8 qb[8];
    {
        const char* qrow = (const char*)Qt + ((size_t)b * NDIM + m0 + mt * 32 + l31) * 256 + hf * 16;
        #pragma unroll
        for (int s = 0; s < 8; ++s) qb[s] = *(const bf16x8*)(qrow + s * 32);
    }

    // hoisted LDS offsets
    unsigned kOff[8];
    {
        int nn = nt * 32 + l31;
        #pragma unroll
        for (int s = 0; s < 8; ++s)
            kOff[s] = nn * 256 + (((2 * s + hf) ^ (nn & 15)) * 16);
    }
    unsigned vOff[2][4];
    #pragma unroll
    for (int t = 0; t < 2; ++t)
        #pragma unroll
        for (int ca = 0; ca < 4; ++ca) {
            int c = ca * 32 + l31;
            vOff[t][ca] = 16384 + c * 128 + (((nt * 4 + t * 2 + hf) ^ (c & 7)) * 16);
        }

    // staging sources / dests (glds: wave-uniform base + lane*16)
    const char* kSrc[2]; const char* vSrc[2];
    unsigned kDst[2], vDst[2];
    #pragma unroll
    for (int i = 0; i < 2; ++i) {
        int slot = i * 512 + tid;
        int n = slot >> 4, j = slot & 15;
        kSrc[i] = kgb + n * 256 + ((j ^ (n & 15)) * 16);
        kDst[i] = i * 8192 + w * 1024;
        int c = slot >> 3, j8 = slot & 7;
        vSrc[i] = vgb + (size_t)c * 8192 + ((j8 ^ (c & 7)) * 16);
        vDst[i] = 16384 + i * 8192 + w * 1024;
    }

    f32x16 oacc[4];
    #pragma unroll
    for (int ca = 0; ca < 4; ++ca)
        #pragma unroll
        for (int i = 0; i < 16; ++i) oacc[ca][i] = 0.f;
    float lacc = 0.f;

    // prologue: stage tile 0 into buf0
    #pragma unroll
    for (int i = 0; i < 2; ++i) { glds16(kSrc[i], smem + kDst[i]); kSrc[i] += 16384; }
    #pragma unroll
    for (int i = 0; i < 2; ++i) { glds16(vSrc[i], smem + vDst[i]); vSrc[i] += 128; }

    auto body = [&](const unsigned bo, const bool do_pref) {
        // tile(bo) ready: its glds issued one body ago; everyone exited prev body
        asm volatile("s_waitcnt vmcnt(0) lgkmcnt(0)\ns_barrier" ::: "memory");
        // prefetch next tile into other buffer immediately (max latency cover)
        if (do_pref) {
            const unsigned obo = bo ^ 32768u;
            #pragma unroll
            for (int i = 0; i < 2; ++i) { glds16(kSrc[i], smem + (obo + kDst[i])); kSrc[i] += 16384; }
            #pragma unroll
            for (int i = 0; i < 2; ++i) { glds16(vSrc[i], smem + (obo + vDst[i])); vSrc[i] += 128; }
        }

        // S^T = K·Q^T : D[n_local][m], 32x32, k=128
        f32x16 st;
        #pragma unroll
        for (int i = 0; i < 16; ++i) st[i] = 0.f;
        #pragma unroll
        for (int s = 0; s < 8; ++s) {
            bf16x8 kf = *(const bf16x8*)(smem + bo + kOff[s]);
            st = mfma32(kf, qb[s], st);
        }

        // P = exp(S-1); pack rows into dwords; C-layout row = (reg&3)+8*(reg>>2)+4*hf
        unsigned d[8];
        float lsum = 0.f;
        #pragma unroll
        for (int rq = 0; rq < 4; ++rq) {
            float e0 = __expf(st[rq * 4 + 0] - 1.0f);
            float e1 = __expf(st[rq * 4 + 1] - 1.0f);
            float e2 = __expf(st[rq * 4 + 2] - 1.0f);
            float e3 = __expf(st[rq * 4 + 3] - 1.0f);
            lsum += (e0 + e1) + (e2 + e3);
            d[rq * 2 + 0] = pack2bf(e0, e1);
            d[rq * 2 + 1] = pack2bf(e2, e3);
        }
        lacc += lsum;
        // cross-half exchange: other half's packed rows
        unsigned o[8];
        #pragma unroll
        for (int j = 0; j < 8; ++j) o[j] = (unsigned)__shfl_xor((int)d[j], 32, 64);
        // build P^T B-frags: kstep t covers n_local = t*16 + hf*8 + j
        bf16x8 pf[2];
        #pragma unroll
        for (int t = 0; t < 2; ++t) {
            u32x4 tv;
            tv.x = hf ? o[4 * t + 2] : d[4 * t + 0];
            tv.y = hf ? o[4 * t + 3] : d[4 * t + 1];
            tv.z = hf ? d[4 * t + 2] : o[4 * t + 0];
            tv.w = hf ? d[4 * t + 3] : o[4 * t + 1];
            pf[t] = __builtin_bit_cast(bf16x8, tv);
        }

        // O^T += V·P^T : wave covers 128c x 32m over its 32-n slice
        #pragma unroll
        for (int t = 0; t < 2; ++t) {
            #pragma unroll
            for (int ca = 0; ca < 4; ++ca) {
                bf16x8 vf = *(const bf16x8*)(smem + bo + vOff[t][ca]);
                oacc[ca] = mfma32(vf, pf[t], oacc[ca]);
            }
        }
    };

    for (int ii = 0; ii < 32; ++ii) {
        body(0u, true);
        body(32768u, ii != 31);
    }

    // ---- epilogue ----
    float lw = lacc + __shfl_xor(lacc, 32, 64);   // full 32-n of this wave's slice
    __syncthreads();                               // E0: tiles fully consumed
    float* lLds = (float*)(smem + 65536);          // [8][32]
    if (lane < 32) lLds[w * 32 + lane] = lw;
    if (w & 1) {                                   // odd waves stage O^T
        float4* dst = (float4*)smem + (w >> 1) * 1024 + lane;
        #pragma unroll
        for (int ca = 0; ca < 4; ++ca)
            #pragma unroll
            for (int rq = 0; rq < 4; ++rq) {
                float4 t = { oacc[ca][rq * 4 + 0], oacc[ca][rq * 4 + 1],
                             oacc[ca][rq * 4 + 2], oacc[ca][rq * 4 + 3] };
                dst[(ca * 4 + rq) * 64] = t;
            }
    }
    __syncthreads();                               // E1
    char* sAgg = smem + 67584;                     // bf16 [128 m][128 c] swizzled
    if (!(w & 1)) {                                // even waves combine + normalize
        float linv = 1.0f / (lLds[w * 32 + l31] + lLds[(w + 1) * 32 + l31]);
        const float4* srcp = (const float4*)smem + (w >> 1) * 1024 + lane;
        int m = (w >> 1) * 32 + l31;
        char* aggRow = sAgg + m * 256;
        const int mx = (m & 7) << 1;
        #pragma unroll
        for (int ca = 0; ca < 4; ++ca)
            #pragma unroll
            for (int rq = 0; rq < 4; ++rq) {
                float4 ov = srcp[(ca * 4 + rq) * 64];
                float v0 = (oacc[ca][rq * 4 + 0] + ov.x) * linv;
                float v1 = (oacc[ca][rq * 4 + 1] + ov.y) * linv;
                float v2 = (oacc[ca][rq * 4 + 2] + ov.z) * linv;
                float v3 = (oacc[ca][rq * 4 + 3] + ov.w) * linv;
                int cq = ca * 8 + rq * 2 + hf;     // c-quad of rows (reg-quad)
                uint2 pk; pk.x = pack2bf(v0, v1); pk.y = pack2bf(v2, v3);
                *(uint2*)(aggRow + ((cq ^ mx) * 8)) = pk;
            }
    }
    __syncthreads();                               // E2: sAgg ready

    // projection (16x16 MFMA): wave -> m-slice w*16, all 128 o
    const int li = lane & 15, q = lane >> 4;
    const int pm = w * 16 + li;
    f32x4 racc[8];
    #pragma unroll
    for (int ob = 0; ob < 8; ++ob) { racc[ob][0]=0.f; racc[ob][1]=0.f; racc[ob][2]=0.f; racc[ob][3]=0.f; }
    #pragma unroll
    for (int ks = 0; ks < 4; ++ks) {
        int slot8 = ((ks * 4 + q) * 2) ^ ((li & 7) << 1);
        bf16x8 af = *(const bf16x8*)(sAgg + pm * 256 + slot8 * 8);
        #pragma unroll
        for (int ob = 0; ob < 8; ++ob) {
            bf16x8 wf = *(const bf16x8*)((const char*)wT + (ob * 16 + li) * 256 + ks * 64 + q * 16);
            racc[ob] = mfma16(af, wf, racc[ob]);
        }
    }

    // LeakyReLU + BN(eval) -> transpose buffer
    float* sRes = (float*)smem;                    // [128 o][132 m]
    #pragma unroll
    for (int ob = 0; ob < 8; ++ob) {
        int oo = ob * 16 + li;
        float sc = scale[oo], bi = bias[oo];
        #pragma unroll
        for (int r = 0; r < 4; ++r) {
            float v = racc[ob][r];
            v = (v >= 0.0f) ? v : 0.01f * v;
            v = v * sc + bi;
            sRes[oo * 132 + w * 16 + q * 4 + r] = v;
        }
    }
    __syncthreads();                               // E3

    // coalesced store: out[b][o][m0..m0+127]
    float* outb = out + (size_t)b * CDIM * NDIM + m0;
    #pragma unroll
    for (int i = 0; i < 8; ++i) {
        int f = tid + i * 512;                     // 4096 float4s
        int o = f >> 5, mq = f & 31;
        *(float4*)(outb + (size_t)o * NDIM + mq * 4) = *(const float4*)(sRes + o * 132 + mq * 4);
    }
}

extern "C" void kernel_launch(void* const* d_in, const int* in_sizes, int n_in,
                              void* d_out, int out_size, void* d_ws, size_t ws_size,
                              hipStream_t stream) {
    const float* input  = (const float*)d_in[0];
    const float* tg     = (const float*)d_in[1];
    const float* weight = (const float*)d_in[2];
    const float* gamma  = (const float*)d_in[3];
    const float* beta   = (const float*)d_in[4];
    const float* rmean  = (const float*)d_in[5];
    const float* rvar   = (const float*)d_in[6];
    float* out = (float*)d_out;

    (void)in_sizes; (void)n_in; (void)out_size; (void)ws_size;

    hipFuncSetAttribute(reinterpret_cast<const void*>(flash5),
                        hipFuncAttributeMaxDynamicSharedMemorySize, 100352);

    dim3 gprep(NDIM / 64, BATCH, 2);
    prep_nt<<<gprep, 256, 0, stream>>>(input, tg, weight, gamma, beta, rmean, rvar, d_ws);
    flash5<<<dim3(256), 512, 100352, stream>>>(d_ws, out);
}